// Round 1
// baseline (1619.211 us; speedup 1.0000x reference)
//
#include <hip/hip_runtime.h>
#include <math.h>

#define HH 28
#define WW 28
#define PP 784
#define CC 128
#define GG 64
#define TT 16
#define LDT 20   // LDS transposed row stride (pad: 16B-aligned rows, non-pow2 banks)

// ws float offsets
#define OFF_FMT0 0
#define OFF_FMT1 100352
#define OFF_FGT0 200704
#define OFF_FGT1 250880
#define OFF_ACCM0 301056
#define OFF_ACCM1 401408
#define OFF_ACCG0 501760
#define OFF_ACCG1 551936
#define OFF_ACCW0 602112
#define OFF_ACCW1 602896
#define ACC_FLOATS 302624   // accm0..accw1 inclusive

struct KArgs {
  const float* fm[2]; const float* fg[2];
  const float* flow[2]; const float* sx[2]; const float* sy[2];
  const float* Wi; const float* Wz; const float* Wdt; const float* bdt;
  const float* alog; const float* Wo; const float* Wyg;
  float* fmT[2]; float* fgT[2];
  float* accm[2]; float* accg[2]; float* accw[2];
  float* out;
};

__global__ void k_zero(float* p, int n) {
  int j = blockIdx.x * 256 + threadIdx.x;
  if (j < n) p[j] = 0.f;
}

__global__ void k_prep(KArgs a) {
  int j = blockIdx.x * 256 + threadIdx.x;     // 301056 jobs exactly
  int side = j / 150528; int r = j - side * 150528;
  int p = r / 192; int ch = r - p * 192;
  if (ch < CC) a.fmT[side][p * CC + ch] = a.fm[side][ch * PP + p];
  else         a.fgT[side][p * GG + (ch - CC)] = a.fg[side][(ch - CC) * PP + p];
}

__global__ void k_fin(KArgs a) {
  int j = blockIdx.x * 256 + threadIdx.x;     // 301056 jobs exactly
  int side = j / 150528; int r = j - side * 150528;
  int p = r / 192; int ch = r - p * 192;
  float inv = 1.f / fmaxf(a.accw[side][p], 1e-6f);
  if (ch < CC) a.out[side * 100352 + ch * PP + p] = a.accm[side][p * CC + ch] * inv;
  else         a.out[200704 + side * 50176 + (ch - CC) * PP + p] = a.accg[side][p * GG + (ch - CC)] * inv;
}

// [tlen<=16, K] x [K, 128] matvec-GEMM piece: thread owns output col o,
// 8 tokens (base..base+7) in registers; weight row stride is 128.
__device__ __forceinline__ void gemmK(const float* __restrict__ W, const float* __restrict__ srcT,
                                      int K, int o, int base, float (&acc)[8]) {
#pragma unroll
  for (int k = 0; k < 8; ++k) acc[k] = 0.f;
  const float* Wp = W + o;
#pragma unroll 4
  for (int c = 0; c < K; ++c) {
    float wv = Wp[c * CC];
    const float4 a0 = *(const float4*)&srcT[c * LDT + base];
    const float4 a1 = *(const float4*)&srcT[c * LDT + base + 4];
    acc[0] = fmaf(a0.x, wv, acc[0]); acc[1] = fmaf(a0.y, wv, acc[1]);
    acc[2] = fmaf(a0.z, wv, acc[2]); acc[3] = fmaf(a0.w, wv, acc[3]);
    acc[4] = fmaf(a1.x, wv, acc[4]); acc[5] = fmaf(a1.y, wv, acc[5]);
    acc[6] = fmaf(a1.z, wv, acc[6]); acc[7] = fmaf(a1.w, wv, acc[7]);
  }
}

__launch_bounds__(256, 2)
__global__ void k_main(KArgs a) {
  __shared__ __align__(16) float smT[CC * LDT];
  __shared__ __align__(16) float sgT[GG * LDT];
  __shared__ __align__(16) float uT[CC * LDT];
  __shared__ __align__(16) float yT[CC * LDT];
  __shared__ __align__(16) float zz[TT * CC];
  __shared__ __align__(16) float dd[TT * CC];
  __shared__ float hs[2 * CC];
  __shared__ float na[2 * CC];
  __shared__ float bbf[2 * CC];
  __shared__ float pw_l[232];
  __shared__ int   tap_i[TT * 4];
  __shared__ float tap_w[TT * 4];
  __shared__ int   sc_i[TT];
  __shared__ float sc_w[TT];
  __shared__ float rms_m[TT], rms_g[TT];
  __shared__ float red[4];

  const int p = blockIdx.x, side = blockIdx.y, tid = threadIdx.x;
  const float avg = 0.5f * (a.sx[side][p] + a.sy[side][p]);
  int si, s;
  if      (fabsf(avg - 15.f) < 1.5f) { si = 0; s = 15; }
  else if (fabsf(avg - 9.f)  < 1.5f) { si = 1; s = 9; }
  else if (fabsf(avg - 5.f)  < 1.5f) { si = 2; s = 5; }
  else return;                                  // unassigned: contributes nothing
  const int hspan = s >> 1, L = s * s;
  const int py = p / WW, px = p - py * WW;
  const float fdx = a.flow[side][p * 4 + 0], fdy = a.flow[side][p * 4 + 1];
  const float cy = fminf(fmaxf((float)py + fdy, 0.f), (float)(HH - 1));
  const float cx = fminf(fmaxf((float)px + fdx, 0.f), (float)(WW - 1));
  const float* fmT = a.fmT[side]; const float* fgT = a.fgT[side];
  float* accm = a.accm[side]; float* accg = a.accg[side]; float* accw = a.accw[side];
  const float* Wib = a.Wi  + si * 2 * CC * CC;
  const float* Wzb = a.Wz  + si * 2 * GG * CC;
  const float* Wdb = a.Wdt + si * 2 * CC * CC;
  const float* Wob = a.Wo  + si * 2 * CC * CC;
  const float* Wyb = a.Wyg + si * 2 * CC * GG;

  { const int d2 = tid >> 7, c2 = tid & 127;
    na[tid]  = -expf(a.alog[(si * 2 + d2) * CC + c2]);
    bbf[tid] = a.bdt[(si * 2 + d2) * CC + c2];
    hs[tid]  = 0.f; }
  if (tid < L) {
    const int dyi = tid / s - hspan, dxi = tid % s - hspan;
    pw_l[tid] = expf(-sqrtf((float)(dyi * dyi + dxi * dxi)) / (0.5f * (float)s));
  }
  __syncthreads();
  { float v = (tid < L) ? pw_l[tid] : 0.f;
#pragma unroll
    for (int off = 32; off > 0; off >>= 1) v += __shfl_xor(v, off);
    if ((tid & 63) == 0) red[tid >> 6] = v; }
  __syncthreads();
  { const float pinv = 1.f / (red[0] + red[1] + red[2] + red[3]);
    if (tid < L) pw_l[tid] *= pinv; }
  __syncthreads();

  for (int t0 = 0; t0 < L; t0 += TT) {
    const int tlen = min(TT, L - t0);
    // per-token tap + scatter precompute
    if (tid < tlen) {
      const int t = t0 + tid;
      const int tq = t / s;
      const int dyi = tq - hspan, dxi = (t - tq * s) - hspan;
      const float ys = cy + (float)dyi, xs = cx + (float)dxi;
      const float y0f = floorf(ys), x0f = floorf(xs);
      const float wy = ys - y0f, wx = xs - x0f;
      const int y0 = (int)y0f, x0 = (int)x0f;
#pragma unroll
      for (int k = 0; k < 4; ++k) {
        const int yi = y0 + (k >> 1), xi = x0 + (k & 1);
        const bool v = (yi >= 0) && (yi < HH) && (xi >= 0) && (xi < WW);
        const int yc = min(max(yi, 0), HH - 1), xc = min(max(xi, 0), WW - 1);
        tap_i[tid * 4 + k] = yc * WW + xc;
        const float wgt = ((k >> 1) ? wy : 1.f - wy) * ((k & 1) ? wx : 1.f - wx);
        tap_w[tid * 4 + k] = v ? wgt : 0.f;
      }
      const int ty = py + dyi, tx = px + dxi;
      const bool sv = (ty >= 0) && (ty < HH) && (tx >= 0) && (tx < WW);
      const int sid2 = sv ? ty * WW + tx : 0;
      const float sw = sv ? pw_l[t] : 0.f;
      sc_i[tid] = sid2; sc_w[tid] = sw;
      if (sw != 0.f) atomicAdd(&accw[sid2], sw);
    }
    __syncthreads();
    // bilinear sampling into transposed LDS tiles
    for (int j = tid; j < tlen * 192; j += 256) {
      const int tt = j / 192, ch = j - tt * 192;
      const int* ti = &tap_i[tt * 4]; const float* tw = &tap_w[tt * 4];
      if (ch < CC) {
        const float v = tw[0] * fmT[ti[0] * CC + ch] + tw[1] * fmT[ti[1] * CC + ch]
                      + tw[2] * fmT[ti[2] * CC + ch] + tw[3] * fmT[ti[3] * CC + ch];
        smT[ch * LDT + tt] = v;
      } else {
        const int gc = ch - CC;
        const float v = tw[0] * fgT[ti[0] * GG + gc] + tw[1] * fgT[ti[1] * GG + gc]
                      + tw[2] * fgT[ti[2] * GG + gc] + tw[3] * fgT[ti[3] * GG + gc];
        sgT[gc * LDT + tt] = v;
      }
    }
    __syncthreads();

    for (int d = 0; d < 2; ++d) {
      const float* Wi = Wib + d * CC * CC;
      const float* Wz = Wzb + d * GG * CC;
      const float* Wd = Wdb + d * CC * CC;
      const float* Wo = Wob + d * CC * CC;
      const float* Wy = Wyb + d * CC * GG;
      // rmsnorm scales (factored out of the GEMMs)
      { const int lane = tid & 63, wv2 = tid >> 6;
#pragma unroll
        for (int j2 = 0; j2 < 4; ++j2) {
          const int tt = wv2 * 4 + j2;
          const float m0 = smT[lane * LDT + tt], m1 = smT[(lane + 64) * LDT + tt];
          const float g0 = sgT[lane * LDT + tt];
          float ssm = m0 * m0 + m1 * m1, ssg = g0 * g0;
#pragma unroll
          for (int off = 32; off > 0; off >>= 1) { ssm += __shfl_xor(ssm, off); ssg += __shfl_xor(ssg, off); }
          if (lane == 0) { rms_m[tt] = rsqrtf(ssm * (1.f / CC) + 1e-5f);
                           rms_g[tt] = rsqrtf(ssg * (1.f / GG) + 1e-5f); }
        } }
      __syncthreads();
      // u = rmsnorm(m) @ Wi ; z = silu(rmsnorm(g) @ Wz)
      { const int o = tid & 127, base = (tid >> 7) * 8;
        float acc[8];
        gemmK(Wi, smT, CC, o, base, acc);
#pragma unroll
        for (int k = 0; k < 8; ++k) uT[o * LDT + base + k] = acc[k] * rms_m[base + k];
        gemmK(Wz, sgT, GG, o, base, acc);
#pragma unroll
        for (int k = 0; k < 8; ++k) { const float zp = acc[k] * rms_g[base + k];
          zz[(base + k) * CC + o] = zp / (1.f + expf(-zp)); } }
      __syncthreads();
      // delta = softplus(u @ Wdt + b)
      { const int o = tid & 127, base = (tid >> 7) * 8;
        float acc[8];
        gemmK(Wd, uT, CC, o, base, acc);
#pragma unroll
        for (int k = 0; k < 8; ++k) { const float x = acc[k] + bbf[d * CC + o];
          dd[(base + k) * CC + o] = fmaxf(x, 0.f) + log1pf(expf(-fabsf(x))); } }
      __syncthreads();
      // fused decay/x_in/scan/y  (lane = channel, serial over tile tokens)
      if (tid < CC) {
        const int c = tid; float h = hs[d * CC + c]; const float nac = na[d * CC + c];
        for (int tt = 0; tt < tlen; ++tt) {
          const float dlt = dd[tt * CC + c];
          const float uv  = uT[c * LDT + tt];
          h = expf(dlt * nac) * h + dlt * uv;
          yT[c * LDT + tt] = h * zz[tt * CC + c];
        }
        hs[d * CC + c] = h;
      }
      __syncthreads();
      // m += y @ Wo
      { const int o = tid & 127, base = (tid >> 7) * 8;
        float acc[8];
        gemmK(Wo, yT, CC, o, base, acc);
#pragma unroll
        for (int k = 0; k < 8; ++k) smT[o * LDT + base + k] += acc[k]; }
      // g += silu(y @ Wyg)   (64 outputs, 4 token-groups of 4)
      { const int o = tid & 63, b4 = (tid >> 6) * 4;
        float a4[4] = {0.f, 0.f, 0.f, 0.f};
        const float* Wp = Wy + o;
#pragma unroll 4
        for (int c = 0; c < CC; ++c) {
          const float wv = Wp[c * GG];
          const float4 ya = *(const float4*)&yT[c * LDT + b4];
          a4[0] = fmaf(ya.x, wv, a4[0]); a4[1] = fmaf(ya.y, wv, a4[1]);
          a4[2] = fmaf(ya.z, wv, a4[2]); a4[3] = fmaf(ya.w, wv, a4[3]);
        }
#pragma unroll
        for (int k = 0; k < 4; ++k) { const float x = a4[k];
          sgT[o * LDT + b4 + k] += x / (1.f + expf(-x)); } }
      __syncthreads();
    }

    // scatter-accumulate final m/g for this tile
    for (int j = tid; j < tlen * 192; j += 256) {
      const int tt = j / 192, ch = j - tt * 192;
      const float w = sc_w[tt];
      if (w != 0.f) {
        const int tgt = sc_i[tt];
        if (ch < CC) atomicAdd(&accm[tgt * CC + ch], smT[ch * LDT + tt] * w);
        else         atomicAdd(&accg[tgt * GG + (ch - CC)], sgT[(ch - CC) * LDT + tt] * w);
      }
    }
    __syncthreads();   // protect LDS tiles before next tile's sampling
  }
}

extern "C" void kernel_launch(void* const* d_in, const int* in_sizes, int n_in,
                              void* d_out, int out_size, void* d_ws, size_t ws_size,
                              hipStream_t stream) {
  (void)in_sizes; (void)n_in; (void)out_size; (void)ws_size;
  float* ws = (float*)d_ws;
  KArgs a;
  a.fm[0]  = (const float*)d_in[0]; a.fm[1]  = (const float*)d_in[1];
  a.fg[0]  = (const float*)d_in[2]; a.fg[1]  = (const float*)d_in[3];
  a.flow[0] = (const float*)d_in[4]; a.flow[1] = (const float*)d_in[5];
  a.sx[0] = (const float*)d_in[6]; a.sy[0] = (const float*)d_in[7];
  a.sx[1] = (const float*)d_in[8]; a.sy[1] = (const float*)d_in[9];
  a.Wi  = (const float*)d_in[10]; a.Wz   = (const float*)d_in[11];
  a.Wdt = (const float*)d_in[12]; a.bdt  = (const float*)d_in[13];
  a.alog = (const float*)d_in[14]; a.Wo  = (const float*)d_in[15];
  a.Wyg = (const float*)d_in[16];
  a.fmT[0] = ws + OFF_FMT0; a.fmT[1] = ws + OFF_FMT1;
  a.fgT[0] = ws + OFF_FGT0; a.fgT[1] = ws + OFF_FGT1;
  a.accm[0] = ws + OFF_ACCM0; a.accm[1] = ws + OFF_ACCM1;
  a.accg[0] = ws + OFF_ACCG0; a.accg[1] = ws + OFF_ACCG1;
  a.accw[0] = ws + OFF_ACCW0; a.accw[1] = ws + OFF_ACCW1;
  a.out = (float*)d_out;

  k_zero<<<1183, 256, 0, stream>>>(ws + OFF_ACCM0, ACC_FLOATS);
  k_prep<<<1176, 256, 0, stream>>>(a);
  k_main<<<dim3(PP, 2), 256, 0, stream>>>(a);
  k_fin<<<1176, 256, 0, stream>>>(a);
}

// Round 2
// 1025.442 us; speedup vs baseline: 1.5790x; 1.5790x over previous
//
#include <hip/hip_runtime.h>
#include <math.h>

#define HH 28
#define WW 28
#define PP 784
#define CC 128
#define GG 64
#define TT 16
#define LDT 20   // LDS transposed row stride (16B-aligned rows)

// ws float offsets
#define OFF_FMT0 0
#define OFF_FMT1 100352
#define OFF_FGT0 200704
#define OFF_FGT1 250880
#define OFF_ACCM0 301056
#define OFF_ACCM1 401408
#define OFF_ACCG0 501760
#define OFF_ACCG1 551936
#define OFF_ACCW0 602112
#define OFF_ACCW1 602896
#define ACC_FLOATS 302624   // accm0..accw1 inclusive
#define OFF_CNT   603680    // 4 ints
#define OFF_CNT2  603684    // 4 ints
#define OFF_NJOBS 603688    // 1 int
#define OFF_JOB   603692    // 1568 ints

struct KArgs {
  const float* fm[2]; const float* fg[2];
  const float* flow[2]; const float* sx[2]; const float* sy[2];
  const float* Wi; const float* Wz; const float* Wdt; const float* bdt;
  const float* alog; const float* Wo; const float* Wyg;
  float* fmT[2]; float* fgT[2];
  float* accm[2]; float* accg[2]; float* accw[2];
  int* cnt; int* cnt2; int* njobs; int* job;
  float* out;
};

__device__ __forceinline__ int span_group(float avg, int& s) {
  if (fabsf(avg - 15.f) < 1.5f) { s = 15; return 0; }
  if (fabsf(avg - 9.f)  < 1.5f) { s = 9;  return 1; }
  if (fabsf(avg - 5.f)  < 1.5f) { s = 5;  return 2; }
  s = 0; return 3;
}

__device__ __forceinline__ float fast_silu(float x) {
  return x * __builtin_amdgcn_rcpf(1.f + __expf(-x));
}

__global__ void k_zero(float* p, int n) {
  int j = blockIdx.x * 256 + threadIdx.x;
  if (j < n) p[j] = 0.f;
}

__global__ void k_prep(KArgs a) {
  int j = blockIdx.x * 256 + threadIdx.x;     // 301056 jobs exactly
  int side = j / 150528; int r = j - side * 150528;
  int p = r / 192; int ch = r - p * 192;
  if (ch < CC) a.fmT[side][p * CC + ch] = a.fm[side][ch * PP + p];
  else         a.fgT[side][p * GG + (ch - CC)] = a.fg[side][(ch - CC) * PP + p];
}

__global__ void k_count(KArgs a) {
  int j = blockIdx.x * 256 + threadIdx.x;
  if (j >= 2 * PP) return;
  int side = j / PP, p = j - side * PP;
  float avg = 0.5f * (a.sx[side][p] + a.sy[side][p]);
  int s; int g = span_group(avg, s);
  if (g < 3) atomicAdd(&a.cnt[g], 1);
}

__global__ void k_assign(KArgs a) {
  int j = blockIdx.x * 256 + threadIdx.x;
  if (j >= 2 * PP) return;
  if (j == 0) a.njobs[0] = a.cnt[0] + a.cnt[1] + a.cnt[2];
  int side = j / PP, p = j - side * PP;
  float avg = 0.5f * (a.sx[side][p] + a.sy[side][p]);
  int s; int g = span_group(avg, s);
  if (g < 3) {
    int base = (g > 0 ? a.cnt[0] : 0) + (g > 1 ? a.cnt[1] : 0);
    int slot = base + atomicAdd(&a.cnt2[g], 1);
    a.job[slot] = (side << 10) | p;
  }
}

__global__ void k_fin(KArgs a) {
  int j = blockIdx.x * 256 + threadIdx.x;     // 301056 jobs exactly
  int side = j / 150528; int r = j - side * 150528;
  int p = r / 192; int ch = r - p * 192;
  float inv = 1.f / fmaxf(a.accw[side][p], 1e-6f);
  if (ch < CC) a.out[side * 100352 + ch * PP + p] = a.accm[side][p * CC + ch] * inv;
  else         a.out[200704 + side * 50176 + (ch - CC) * PP + p] = a.accg[side][p * GG + (ch - CC)] * inv;
}

// [tlen<=16, K] x [K, 128]: thread owns output col o, 8 tokens in registers.
// srcT reads are wave-uniform (broadcast, conflict-free); W reads coalesced.
__device__ __forceinline__ void gemmK(const float* __restrict__ W, const float* __restrict__ srcT,
                                      int K, int o, int base, float (&acc)[8]) {
#pragma unroll
  for (int k = 0; k < 8; ++k) acc[k] = 0.f;
  const float* Wp = W + o;
#pragma unroll 4
  for (int c = 0; c < K; ++c) {
    float wv = Wp[c * CC];
    const float4 a0 = *(const float4*)&srcT[c * LDT + base];
    const float4 a1 = *(const float4*)&srcT[c * LDT + base + 4];
    acc[0] = fmaf(a0.x, wv, acc[0]); acc[1] = fmaf(a0.y, wv, acc[1]);
    acc[2] = fmaf(a0.z, wv, acc[2]); acc[3] = fmaf(a0.w, wv, acc[3]);
    acc[4] = fmaf(a1.x, wv, acc[4]); acc[5] = fmaf(a1.y, wv, acc[5]);
    acc[6] = fmaf(a1.z, wv, acc[6]); acc[7] = fmaf(a1.w, wv, acc[7]);
  }
}

__launch_bounds__(256, 4)
__global__ void k_main(KArgs a) {
  __shared__ __align__(16) float smT[CC * LDT];
  __shared__ __align__(16) float sgT[GG * LDT];
  __shared__ __align__(16) float uT[CC * LDT];   // doubles as yT after the Wdt GEMM
  __shared__ float hs[2 * CC];
  __shared__ float hseg[CC];
  __shared__ float na[2 * CC];
  __shared__ float bbf[2 * CC];
  __shared__ float pw_l[228];
  __shared__ int   tap_i[TT * 4];
  __shared__ float tap_w[TT * 4];
  __shared__ int   sc_i[TT];
  __shared__ float sc_w[TT];
  __shared__ float rms_m[TT], rms_g[TT];
  __shared__ float red[4];

  const int tid = threadIdx.x;
  if (blockIdx.x >= a.njobs[0]) return;
  const int job = a.job[blockIdx.x];
  const int side = job >> 10, p = job & 1023;
  const float avg = 0.5f * (a.sx[side][p] + a.sy[side][p]);
  int s; const int si = span_group(avg, s);
  const int hspan = s >> 1, L = s * s;
  const int py = p / WW, px = p - py * WW;
  const float fdx = a.flow[side][p * 4 + 0], fdy = a.flow[side][p * 4 + 1];
  const float cy = fminf(fmaxf((float)py + fdy, 0.f), (float)(HH - 1));
  const float cx = fminf(fmaxf((float)px + fdx, 0.f), (float)(WW - 1));
  const float* fmT = a.fmT[side]; const float* fgT = a.fgT[side];
  float* accm = a.accm[side]; float* accg = a.accg[side]; float* accw = a.accw[side];
  const float* Wib = a.Wi  + si * 2 * CC * CC;
  const float* Wzb = a.Wz  + si * 2 * GG * CC;
  const float* Wdb = a.Wdt + si * 2 * CC * CC;
  const float* Wob = a.Wo  + si * 2 * CC * CC;
  const float* Wyb = a.Wyg + si * 2 * CC * GG;

  { const int d2 = tid >> 7, c2 = tid & 127;
    na[tid]  = -__expf(a.alog[(si * 2 + d2) * CC + c2]);
    bbf[tid] = a.bdt[(si * 2 + d2) * CC + c2];
    hs[tid]  = 0.f; }
  if (tid < L) {
    const int dyi = tid / s - hspan, dxi = tid % s - hspan;
    pw_l[tid] = __expf(-sqrtf((float)(dyi * dyi + dxi * dxi)) / (0.5f * (float)s));
  }
  __syncthreads();
  { float v = (tid < L) ? pw_l[tid] : 0.f;
#pragma unroll
    for (int off = 32; off > 0; off >>= 1) v += __shfl_xor(v, off);
    if ((tid & 63) == 0) red[tid >> 6] = v; }
  __syncthreads();
  { const float pinv = 1.f / (red[0] + red[1] + red[2] + red[3]);
    if (tid < L) pw_l[tid] *= pinv; }
  __syncthreads();

  for (int t0 = 0; t0 < L; t0 += TT) {
    const int tlen = min(TT, L - t0);
    // per-token tap + scatter precompute
    if (tid < tlen) {
      const int t = t0 + tid;
      const int tq = t / s;
      const int dyi = tq - hspan, dxi = (t - tq * s) - hspan;
      const float ys = cy + (float)dyi, xs = cx + (float)dxi;
      const float y0f = floorf(ys), x0f = floorf(xs);
      const float wy = ys - y0f, wx = xs - x0f;
      const int y0 = (int)y0f, x0 = (int)x0f;
#pragma unroll
      for (int k = 0; k < 4; ++k) {
        const int yi = y0 + (k >> 1), xi = x0 + (k & 1);
        const bool v = (yi >= 0) && (yi < HH) && (xi >= 0) && (xi < WW);
        const int yc = min(max(yi, 0), HH - 1), xc = min(max(xi, 0), WW - 1);
        tap_i[tid * 4 + k] = yc * WW + xc;
        const float wgt = ((k >> 1) ? wy : 1.f - wy) * ((k & 1) ? wx : 1.f - wx);
        tap_w[tid * 4 + k] = v ? wgt : 0.f;
      }
      const int ty = py + dyi, tx = px + dxi;
      const bool sv = (ty >= 0) && (ty < HH) && (tx >= 0) && (tx < WW);
      const int sid2 = sv ? ty * WW + tx : 0;
      const float sw = sv ? pw_l[t] : 0.f;
      sc_i[tid] = sid2; sc_w[tid] = sw;
      if (sw != 0.f) atomicAdd(&accw[sid2], sw);
    }
    __syncthreads();
    // bilinear sampling into transposed LDS tiles
    for (int j = tid; j < tlen * 192; j += 256) {
      const int tt = j / 192, ch = j - tt * 192;
      const int* ti = &tap_i[tt * 4]; const float* tw = &tap_w[tt * 4];
      if (ch < CC) {
        const float v = tw[0] * fmT[ti[0] * CC + ch] + tw[1] * fmT[ti[1] * CC + ch]
                      + tw[2] * fmT[ti[2] * CC + ch] + tw[3] * fmT[ti[3] * CC + ch];
        smT[ch * LDT + tt] = v;
      } else {
        const int gc = ch - CC;
        const float v = tw[0] * fgT[ti[0] * GG + gc] + tw[1] * fgT[ti[1] * GG + gc]
                      + tw[2] * fgT[ti[2] * GG + gc] + tw[3] * fgT[ti[3] * GG + gc];
        sgT[gc * LDT + tt] = v;
      }
    }
    __syncthreads();

    for (int d = 0; d < 2; ++d) {
      const float* Wi = Wib + d * CC * CC;
      const float* Wz = Wzb + d * GG * CC;
      const float* Wd = Wdb + d * CC * CC;
      const float* Wo = Wob + d * CC * CC;
      const float* Wy = Wyb + d * CC * GG;
      // rmsnorm scales (factored out of the GEMMs)
      { const int lane = tid & 63, wv2 = tid >> 6;
#pragma unroll
        for (int j2 = 0; j2 < 4; ++j2) {
          const int tt = wv2 * 4 + j2;
          const float m0 = smT[lane * LDT + tt], m1 = smT[(lane + 64) * LDT + tt];
          const float g0 = sgT[lane * LDT + tt];
          float ssm = m0 * m0 + m1 * m1, ssg = g0 * g0;
#pragma unroll
          for (int off = 32; off > 0; off >>= 1) { ssm += __shfl_xor(ssm, off); ssg += __shfl_xor(ssg, off); }
          if (lane == 0) { rms_m[tt] = rsqrtf(ssm * (1.f / CC) + 1e-5f);
                           rms_g[tt] = rsqrtf(ssg * (1.f / GG) + 1e-5f); }
        } }
      __syncthreads();

      const int o = tid & 127, seg = tid >> 7, base = seg * 8;
      float u[8], z[8];
      // u = rmsnorm(m) @ Wi  (write to LDS for the Wdt GEMM; keep in regs for x_in)
      gemmK(Wi, smT, CC, o, base, u);
#pragma unroll
      for (int k = 0; k < 8; ++k) { u[k] *= rms_m[base + k]; uT[o * LDT + base + k] = u[k]; }
      // z = silu(rmsnorm(g) @ Wz)  (registers only)
      gemmK(Wz, sgT, GG, o, base, z);
#pragma unroll
      for (int k = 0; k < 8; ++k) z[k] = fast_silu(z[k] * rms_g[base + k]);
      __syncthreads();

      // delta/decay/x_in token-parallel; 2-segment scan in registers
      float acc[8];
      gemmK(Wd, uT, CC, o, base, acc);
      const float bo = bbf[d * CC + o], nac = na[d * CC + o];
      float Pk[8], Dk[8];
      if (seg == 0) {
        float h = hs[d * CC + o];
#pragma unroll
        for (int k = 0; k < 8; ++k) {
          const float x = acc[k] + bo;
          float dlt = fmaxf(x, 0.f) + __logf(1.f + __expf(-fabsf(x)));
          float dec = __expf(dlt * nac), xin = dlt * u[k];
          if (k >= tlen) { dec = 1.f; xin = 0.f; }
          h = dec * h + xin;
          Pk[k] = h;                       // h values; multiply by z after sync
        }
        hseg[o] = h;
      } else {
        float P = 0.f, D = 1.f;
#pragma unroll
        for (int k = 0; k < 8; ++k) {
          const float x = acc[k] + bo;
          float dlt = fmaxf(x, 0.f) + __logf(1.f + __expf(-fabsf(x)));
          float dec = __expf(dlt * nac), xin = dlt * u[k];
          if (8 + k >= tlen) { dec = 1.f; xin = 0.f; }
          P = dec * P + xin; D *= dec;
          Pk[k] = P; Dk[k] = D;
        }
      }
      __syncthreads();                      // uT fully consumed; hseg ready
      if (seg == 0) {
#pragma unroll
        for (int k = 0; k < 8; ++k) uT[o * LDT + k] = Pk[k] * z[k];          // y
      } else {
        const float h7 = hseg[o];
#pragma unroll
        for (int k = 0; k < 8; ++k) uT[o * LDT + 8 + k] = (Dk[k] * h7 + Pk[k]) * z[k];
        hs[d * CC + o] = Dk[7] * h7 + Pk[7];
      }
      __syncthreads();

      // m += y @ Wo
      gemmK(Wo, uT, CC, o, base, acc);
#pragma unroll
      for (int k = 0; k < 8; ++k) smT[o * LDT + base + k] += acc[k];
      // g += silu(y @ Wyg)
      { const int o2 = tid & 63, b4 = (tid >> 6) * 4;
        float a4[4] = {0.f, 0.f, 0.f, 0.f};
        const float* Wp = Wy + o2;
#pragma unroll 4
        for (int c = 0; c < CC; ++c) {
          const float wv = Wp[c * GG];
          const float4 ya = *(const float4*)&uT[c * LDT + b4];
          a4[0] = fmaf(ya.x, wv, a4[0]); a4[1] = fmaf(ya.y, wv, a4[1]);
          a4[2] = fmaf(ya.z, wv, a4[2]); a4[3] = fmaf(ya.w, wv, a4[3]);
        }
#pragma unroll
        for (int k = 0; k < 4; ++k) sgT[o2 * LDT + b4 + k] += fast_silu(a4[k]); }
      __syncthreads();
    }

    // scatter-accumulate final m/g for this tile
    for (int j = tid; j < tlen * 192; j += 256) {
      const int tt = j / 192, ch = j - tt * 192;
      const float w = sc_w[tt];
      if (w != 0.f) {
        const int tgt = sc_i[tt];
        if (ch < CC) atomicAdd(&accm[tgt * CC + ch], smT[ch * LDT + tt] * w);
        else         atomicAdd(&accg[tgt * GG + (ch - CC)], sgT[(ch - CC) * LDT + tt] * w);
      }
    }
    __syncthreads();   // protect LDS tiles before next tile's sampling
  }
}

extern "C" void kernel_launch(void* const* d_in, const int* in_sizes, int n_in,
                              void* d_out, int out_size, void* d_ws, size_t ws_size,
                              hipStream_t stream) {
  (void)in_sizes; (void)n_in; (void)out_size; (void)ws_size;
  float* ws = (float*)d_ws;
  KArgs a;
  a.fm[0]  = (const float*)d_in[0]; a.fm[1]  = (const float*)d_in[1];
  a.fg[0]  = (const float*)d_in[2]; a.fg[1]  = (const float*)d_in[3];
  a.flow[0] = (const float*)d_in[4]; a.flow[1] = (const float*)d_in[5];
  a.sx[0] = (const float*)d_in[6]; a.sy[0] = (const float*)d_in[7];
  a.sx[1] = (const float*)d_in[8]; a.sy[1] = (const float*)d_in[9];
  a.Wi  = (const float*)d_in[10]; a.Wz   = (const float*)d_in[11];
  a.Wdt = (const float*)d_in[12]; a.bdt  = (const float*)d_in[13];
  a.alog = (const float*)d_in[14]; a.Wo  = (const float*)d_in[15];
  a.Wyg = (const float*)d_in[16];
  a.fmT[0] = ws + OFF_FMT0; a.fmT[1] = ws + OFF_FMT1;
  a.fgT[0] = ws + OFF_FGT0; a.fgT[1] = ws + OFF_FGT1;
  a.accm[0] = ws + OFF_ACCM0; a.accm[1] = ws + OFF_ACCM1;
  a.accg[0] = ws + OFF_ACCG0; a.accg[1] = ws + OFF_ACCG1;
  a.accw[0] = ws + OFF_ACCW0; a.accw[1] = ws + OFF_ACCW1;
  a.cnt  = (int*)(ws + OFF_CNT);
  a.cnt2 = (int*)(ws + OFF_CNT2);
  a.njobs = (int*)(ws + OFF_NJOBS);
  a.job  = (int*)(ws + OFF_JOB);
  a.out = (float*)d_out;

  k_zero<<<1183, 256, 0, stream>>>(ws + OFF_ACCM0, ACC_FLOATS + 12);
  k_prep<<<1176, 256, 0, stream>>>(a);
  k_count<<<7, 256, 0, stream>>>(a);
  k_assign<<<7, 256, 0, stream>>>(a);
  k_main<<<1568, 256, 0, stream>>>(a);
  k_fin<<<1176, 256, 0, stream>>>(a);
}

// Round 3
// 327.298 us; speedup vs baseline: 4.9472x; 3.1330x over previous
//
#include <hip/hip_runtime.h>
#include <math.h>

typedef short s16x8 __attribute__((ext_vector_type(8)));
typedef unsigned short u16x8v __attribute__((ext_vector_type(8)));
typedef unsigned short u16x4v __attribute__((ext_vector_type(4)));
typedef float f32x4 __attribute__((ext_vector_type(4)));

#define HH 28
#define WW 28
#define PP 784
#define CC 128
#define GG 64
#define TT 16
#define AST 136   // bf16 activation row stride (16B-aligned rows, 2-way banks only)
#define MST 132   // f32 m-residual row stride
#define GST 68    // f32 g-residual row stride

// ws float offsets
#define OFF_FMT0 0
#define OFF_FMT1 100352
#define OFF_FGT0 200704
#define OFF_FGT1 250880
#define OFF_ACCM0 301056
#define OFF_ACCM1 401408
#define OFF_ACCG0 501760
#define OFF_ACCG1 551936
#define OFF_ACCW0 602112
#define OFF_ACCW1 602896
#define ACC_FLOATS 302624   // accm0..accw1 inclusive
#define OFF_CNT   603680    // 4 ints
#define OFF_CNT2  603684    // 4 ints
#define OFF_NJOBS 603688    // 1 int
#define OFF_JOB   603692    // 1568 ints
#define OFF_WB    605260    // bf16 weights, 393216 ushorts (196608 floats), 16B-aligned

// bf16 weight sub-offsets (ushort units), layout [set=(si*2+d)][out][in]
#define WIB 0
#define WZB 98304
#define WDB 147456
#define WOB 245760
#define WYB 344064

struct KArgs {
  const float* fm[2]; const float* fg[2];
  const float* flow[2]; const float* sx[2]; const float* sy[2];
  const float* Wi; const float* Wz; const float* Wdt; const float* bdt;
  const float* alog; const float* Wo; const float* Wyg;
  float* fmT[2]; float* fgT[2];
  float* accm[2]; float* accg[2]; float* accw[2];
  int* cnt; int* cnt2; int* njobs; int* job;
  unsigned short* wb;
  float* out;
};

__device__ __forceinline__ int span_group(float avg, int& s) {
  if (fabsf(avg - 15.f) < 1.5f) { s = 15; return 0; }
  if (fabsf(avg - 9.f)  < 1.5f) { s = 9;  return 1; }
  if (fabsf(avg - 5.f)  < 1.5f) { s = 5;  return 2; }
  s = 0; return 3;
}

__device__ __forceinline__ float fast_silu(float x) {
  return x * __builtin_amdgcn_rcpf(1.f + __expf(-x));
}

__device__ __forceinline__ unsigned short f2bf(float f) {
  unsigned u = __float_as_uint(f);
  unsigned r = (u + 0x7fffu + ((u >> 16) & 1u)) >> 16;
  return (unsigned short)r;
}

#define MFMA(A_, B_, C_) __builtin_amdgcn_mfma_f32_16x16x32_bf16((A_), (B_), (C_), 0, 0, 0)

__global__ void k_zero(float* p, int n) {
  int j = blockIdx.x * 256 + threadIdx.x;
  if (j < n) p[j] = 0.f;
}

__global__ void k_prep(KArgs a) {
  int j = blockIdx.x * 256 + threadIdx.x;     // 301056 exactly
  int side = j / 150528; int r = j - side * 150528;
  int p = r / 192; int ch = r - p * 192;
  if (ch < CC) a.fmT[side][p * CC + ch] = a.fm[side][ch * PP + p];
  else         a.fgT[side][p * GG + (ch - CC)] = a.fg[side][(ch - CC) * PP + p];
}

// transpose + bf16-convert all weights to [set][out][in]
__global__ void k_prepw(KArgs a) {
  int j = blockIdx.x * 256 + threadIdx.x;     // 393216 exactly
  unsigned short* wb = a.wb;
  if (j < 98304) {
    int set = j >> 14, r = j & 16383; int o = r >> 7, c = r & 127;
    wb[WIB + j] = f2bf(a.Wi[set * 16384 + c * 128 + o]);
  } else if (j < 147456) {
    int r = j - 98304; int set = r >> 13, rr = r & 8191; int o = rr >> 6, c = rr & 63;
    wb[WZB + r] = f2bf(a.Wz[set * 8192 + c * 128 + o]);
  } else if (j < 245760) {
    int r = j - 147456; int set = r >> 14, rr = r & 16383; int o = rr >> 7, c = rr & 127;
    wb[WDB + r] = f2bf(a.Wdt[set * 16384 + c * 128 + o]);
  } else if (j < 344064) {
    int r = j - 245760; int set = r >> 14, rr = r & 16383; int o = rr >> 7, c = rr & 127;
    wb[WOB + r] = f2bf(a.Wo[set * 16384 + c * 128 + o]);
  } else {
    int r = j - 344064; int set = r >> 13, rr = r & 8191; int o = rr >> 7, c = rr & 127;
    wb[WYB + r] = f2bf(a.Wyg[set * 8192 + c * 64 + o]);
  }
}

__global__ void k_count(KArgs a) {
  int j = blockIdx.x * 256 + threadIdx.x;
  if (j >= 2 * PP) return;
  int side = j / PP, p = j - side * PP;
  float avg = 0.5f * (a.sx[side][p] + a.sy[side][p]);
  int s; int g = span_group(avg, s);
  if (g < 3) atomicAdd(&a.cnt[g], 1);
}

__global__ void k_assign(KArgs a) {
  int j = blockIdx.x * 256 + threadIdx.x;
  if (j >= 2 * PP) return;
  if (j == 0) a.njobs[0] = a.cnt[0] + a.cnt[1] + a.cnt[2];
  int side = j / PP, p = j - side * PP;
  float avg = 0.5f * (a.sx[side][p] + a.sy[side][p]);
  int s; int g = span_group(avg, s);
  if (g < 3) {
    int base = (g > 0 ? a.cnt[0] : 0) + (g > 1 ? a.cnt[1] : 0);
    int slot = base + atomicAdd(&a.cnt2[g], 1);
    a.job[slot] = (side << 10) | p;
  }
}

__global__ void k_fin(KArgs a) {
  int j = blockIdx.x * 256 + threadIdx.x;     // 301056 exactly
  int side = j / 150528; int r = j - side * 150528;
  int p = r / 192; int ch = r - p * 192;
  float inv = 1.f / fmaxf(a.accw[side][p], 1e-6f);
  if (ch < CC) a.out[side * 100352 + ch * PP + p] = a.accm[side][p * CC + ch] * inv;
  else         a.out[200704 + side * 50176 + (ch - CC) * PP + p] = a.accg[side][p * GG + (ch - CC)] * inv;
}

__launch_bounds__(256, 4)
__global__ void k_main(KArgs a) {
  __shared__ __align__(16) float mres[TT * MST];
  __shared__ __align__(16) float gres[TT * GST];
  __shared__ __align__(16) unsigned short bufA[TT * AST];
  __shared__ __align__(16) unsigned short bufB[TT * AST];
  __shared__ float hs[2 * CC];
  __shared__ float na_s[2 * CC];
  __shared__ float bb_s[2 * CC];
  __shared__ float pw_l[228];
  __shared__ int   tap_i[TT * 4];
  __shared__ float tap_w[TT * 4];
  __shared__ int   sc_i[TT];
  __shared__ float sc_w[TT];
  __shared__ float red[4];

  const int tid = threadIdx.x;
  if (blockIdx.x >= a.njobs[0]) return;
  const int job = a.job[blockIdx.x];
  const int side = job >> 10, p = job & 1023;
  const float avg = 0.5f * (a.sx[side][p] + a.sy[side][p]);
  int s; const int si = span_group(avg, s);
  const int hspan = s >> 1, L = s * s;
  const int py = p / WW, px = p - py * WW;
  const float fdx = a.flow[side][p * 4 + 0], fdy = a.flow[side][p * 4 + 1];
  const float cy = fminf(fmaxf((float)py + fdy, 0.f), (float)(HH - 1));
  const float cx = fminf(fmaxf((float)px + fdx, 0.f), (float)(WW - 1));
  const float* fmT = a.fmT[side]; const float* fgT = a.fgT[side];
  float* accm = a.accm[side]; float* accg = a.accg[side]; float* accw = a.accw[side];

  const unsigned short* wb = a.wb;
  const int wv = tid >> 6, l = tid & 63, lm = l & 15, g = l >> 4;
  const int o0 = 32 * wv + lm, o1 = o0 + 16, og = 16 * wv + lm;

  { const int d2 = tid >> 7, c2 = tid & 127;
    na_s[tid] = -__expf(a.alog[(si * 2 + d2) * CC + c2]);
    bb_s[tid] = a.bdt[(si * 2 + d2) * CC + c2];
    hs[tid] = 0.f; }
  if (tid < L) {
    const int dyi = tid / s - hspan, dxi = tid % s - hspan;
    pw_l[tid] = __expf(-sqrtf((float)(dyi * dyi + dxi * dxi)) / (0.5f * (float)s));
  }
  __syncthreads();
  { float v = (tid < L) ? pw_l[tid] : 0.f;
#pragma unroll
    for (int off = 32; off > 0; off >>= 1) v += __shfl_xor(v, off);
    if ((tid & 63) == 0) red[tid >> 6] = v; }
  __syncthreads();
  { const float pinv = 1.f / (red[0] + red[1] + red[2] + red[3]);
    if (tid < L) pw_l[tid] *= pinv; }
  __syncthreads();

  for (int t0 = 0; t0 < L; t0 += TT) {
    const int tlen = min(TT, L - t0);
    if (tid < tlen) {
      const int t = t0 + tid;
      const int tq = t / s;
      const int dyi = tq - hspan, dxi = (t - tq * s) - hspan;
      const float ys = cy + (float)dyi, xs = cx + (float)dxi;
      const float y0f = floorf(ys), x0f = floorf(xs);
      const float wy = ys - y0f, wx = xs - x0f;
      const int y0 = (int)y0f, x0 = (int)x0f;
#pragma unroll
      for (int k = 0; k < 4; ++k) {
        const int yi = y0 + (k >> 1), xi = x0 + (k & 1);
        const bool v = (yi >= 0) && (yi < HH) && (xi >= 0) && (xi < WW);
        const int yc = min(max(yi, 0), HH - 1), xc = min(max(xi, 0), WW - 1);
        tap_i[tid * 4 + k] = yc * WW + xc;
        const float wgt = ((k >> 1) ? wy : 1.f - wy) * ((k & 1) ? wx : 1.f - wx);
        tap_w[tid * 4 + k] = v ? wgt : 0.f;
      }
      const int ty = py + dyi, tx = px + dxi;
      const bool sv = (ty >= 0) && (ty < HH) && (tx >= 0) && (tx < WW);
      const int sid2 = sv ? ty * WW + tx : 0;
      const float sw = sv ? pw_l[t] : 0.f;
      sc_i[tid] = sid2; sc_w[tid] = sw;
      if (sw != 0.f) atomicAdd(&accw[sid2], sw);
    }
    __syncthreads();
    // bilinear sampling into token-major f32 residual tiles
    for (int j = tid; j < tlen * 192; j += 256) {
      const int tt = j / 192, ch = j - tt * 192;
      const int* ti = &tap_i[tt * 4]; const float* tw = &tap_w[tt * 4];
      if (ch < CC) {
        mres[tt * MST + ch] = tw[0] * fmT[ti[0] * CC + ch] + tw[1] * fmT[ti[1] * CC + ch]
                            + tw[2] * fmT[ti[2] * CC + ch] + tw[3] * fmT[ti[3] * CC + ch];
      } else {
        const int gc = ch - CC;
        gres[tt * GST + gc] = tw[0] * fgT[ti[0] * GG + gc] + tw[1] * fgT[ti[1] * GG + gc]
                            + tw[2] * fgT[ti[2] * GG + gc] + tw[3] * fgT[ti[3] * GG + gc];
      }
    }

    for (int d = 0; d < 2; ++d) {
      const unsigned short* Wib = wb + WIB + (si * 2 + d) * 16384;
      const unsigned short* Wzb = wb + WZB + (si * 2 + d) * 8192;
      const unsigned short* Wdb = wb + WDB + (si * 2 + d) * 16384;
      const unsigned short* Wob = wb + WOB + (si * 2 + d) * 16384;
      const unsigned short* Wyb = wb + WYB + (si * 2 + d) * 8192;
      __syncthreads();   // residuals stable
      // rmsnorm + bf16 normalized copies (shfl over 16-lane token groups)
      { const int tr = tid >> 4, c16 = tid & 15;
        f32x4 mv0 = *(const f32x4*)&mres[tr * MST + c16 * 8];
        f32x4 mv1 = *(const f32x4*)&mres[tr * MST + c16 * 8 + 4];
        f32x4 gv  = *(const f32x4*)&gres[tr * GST + c16 * 4];
        float ssm = mv0[0]*mv0[0]+mv0[1]*mv0[1]+mv0[2]*mv0[2]+mv0[3]*mv0[3]
                  + mv1[0]*mv1[0]+mv1[1]*mv1[1]+mv1[2]*mv1[2]+mv1[3]*mv1[3];
        float ssg = gv[0]*gv[0]+gv[1]*gv[1]+gv[2]*gv[2]+gv[3]*gv[3];
#pragma unroll
        for (int off = 8; off > 0; off >>= 1) { ssm += __shfl_xor(ssm, off); ssg += __shfl_xor(ssg, off); }
        const float sm = rsqrtf(ssm * (1.f / CC) + 1e-5f);
        const float sg = rsqrtf(ssg * (1.f / GG) + 1e-5f);
        u16x8v xv;
#pragma unroll
        for (int k = 0; k < 4; ++k) { xv[k] = f2bf(mv0[k] * sm); xv[4 + k] = f2bf(mv1[k] * sm); }
        *(u16x8v*)&bufA[tr * AST + c16 * 8] = xv;
        u16x4v gx;
#pragma unroll
        for (int k = 0; k < 4; ++k) gx[k] = f2bf(gv[k] * sg);
        *(u16x4v*)&bufB[tr * AST + c16 * 4] = gx;
      }
      __syncthreads();
      // u = xm @ Wi ; z = silu(xg @ Wz)
      f32x4 u0 = {0.f,0.f,0.f,0.f}, u1 = {0.f,0.f,0.f,0.f};
      f32x4 z0 = {0.f,0.f,0.f,0.f}, z1 = {0.f,0.f,0.f,0.f};
#pragma unroll
      for (int ss = 0; ss < 4; ++ss) {
        const int c0 = 32 * ss + g * 8;
        s16x8 av = *(const s16x8*)&bufA[lm * AST + c0];
        s16x8 b0 = *(const s16x8*)&Wib[(32 * wv + lm) * 128 + c0];
        s16x8 b1 = *(const s16x8*)&Wib[(32 * wv + 16 + lm) * 128 + c0];
        u0 = MFMA(av, b0, u0); u1 = MFMA(av, b1, u1);
      }
#pragma unroll
      for (int ss = 0; ss < 2; ++ss) {
        const int c0 = 32 * ss + g * 8;
        s16x8 av = *(const s16x8*)&bufB[lm * AST + c0];
        s16x8 b0 = *(const s16x8*)&Wzb[(32 * wv + lm) * 64 + c0];
        s16x8 b1 = *(const s16x8*)&Wzb[(32 * wv + 16 + lm) * 64 + c0];
        z0 = MFMA(av, b0, z0); z1 = MFMA(av, b1, z1);
      }
#pragma unroll
      for (int r = 0; r < 4; ++r) { z0[r] = fast_silu(z0[r]); z1[r] = fast_silu(z1[r]); }
      __syncthreads();   // bufA/bufB free
#pragma unroll
      for (int r = 0; r < 4; ++r) {
        bufA[(4 * g + r) * AST + o0] = f2bf(u0[r]);
        bufA[(4 * g + r) * AST + o1] = f2bf(u1[r]);
      }
      __syncthreads();   // u16 visible
      // delta = softplus(u @ Wdt + b)
      f32x4 dt0 = {0.f,0.f,0.f,0.f}, dt1 = {0.f,0.f,0.f,0.f};
#pragma unroll
      for (int ss = 0; ss < 4; ++ss) {
        const int c0 = 32 * ss + g * 8;
        s16x8 av = *(const s16x8*)&bufA[lm * AST + c0];
        s16x8 b0 = *(const s16x8*)&Wdb[(32 * wv + lm) * 128 + c0];
        s16x8 b1 = *(const s16x8*)&Wdb[(32 * wv + 16 + lm) * 128 + c0];
        dt0 = MFMA(av, b0, dt0); dt1 = MFMA(av, b1, dt1);
      }
      // decay/x_in + 4-segment shfl scan (lane holds t = 4g..4g+3 of channels o0,o1)
      const float hp0 = hs[d * CC + o0], hp1 = hs[d * CC + o1];
      const float bb0 = bb_s[d * CC + o0], bb1 = bb_s[d * CC + o1];
      const float na0 = na_s[d * CC + o0], na1 = na_s[d * CC + o1];
      float Pl0[4], Dl0[4], Pl1[4], Dl1[4];
      { float P = 0.f, D = 1.f;
#pragma unroll
        for (int r = 0; r < 4; ++r) {
          const float x = dt0[r] + bb0;
          float dlt = fmaxf(x, 0.f) + __logf(1.f + __expf(-fabsf(x)));
          float dec = __expf(dlt * na0), xin = dlt * u0[r];
          if (4 * g + r >= tlen) { dec = 1.f; xin = 0.f; }
          P = dec * P + xin; D *= dec; Pl0[r] = P; Dl0[r] = D;
        } }
      { float P = 0.f, D = 1.f;
#pragma unroll
        for (int r = 0; r < 4; ++r) {
          const float x = dt1[r] + bb1;
          float dlt = fmaxf(x, 0.f) + __logf(1.f + __expf(-fabsf(x)));
          float dec = __expf(dlt * na1), xin = dlt * u1[r];
          if (4 * g + r >= tlen) { dec = 1.f; xin = 0.f; }
          P = dec * P + xin; D *= dec; Pl1[r] = P; Dl1[r] = D;
        } }
      float Pi0 = Pl0[3], Di0 = Dl0[3], Pi1 = Pl1[3], Di1 = Dl1[3];
      { float pa = __shfl_up(Pi0, 16), da = __shfl_up(Di0, 16);
        float pb = __shfl_up(Pi1, 16), db = __shfl_up(Di1, 16);
        if (g >= 1) { Pi0 = Di0 * pa + Pi0; Di0 *= da; Pi1 = Di1 * pb + Pi1; Di1 *= db; }
        pa = __shfl_up(Pi0, 32); da = __shfl_up(Di0, 32);
        pb = __shfl_up(Pi1, 32); db = __shfl_up(Di1, 32);
        if (g >= 2) { Pi0 = Di0 * pa + Pi0; Di0 *= da; Pi1 = Di1 * pb + Pi1; Di1 *= db; } }
      float Pe0 = __shfl_up(Pi0, 16), De0 = __shfl_up(Di0, 16);
      float Pe1 = __shfl_up(Pi1, 16), De1 = __shfl_up(Di1, 16);
      if (g == 0) { Pe0 = 0.f; De0 = 1.f; Pe1 = 0.f; De1 = 1.f; }
      const float cr0 = De0 * hp0 + Pe0, cr1 = De1 * hp1 + Pe1;
#pragma unroll
      for (int r = 0; r < 4; ++r) {
        const float h0 = Dl0[r] * cr0 + Pl0[r];
        const float h1 = Dl1[r] * cr1 + Pl1[r];
        bufB[(4 * g + r) * AST + o0] = f2bf(h0 * z0[r]);
        bufB[(4 * g + r) * AST + o1] = f2bf(h1 * z1[r]);
      }
      if (g == 3) {
        hs[d * CC + o0] = Dl0[3] * cr0 + Pl0[3];
        hs[d * CC + o1] = Dl1[3] * cr1 + Pl1[3];
      }
      __syncthreads();   // y16 visible
      // m += y @ Wo ; g += silu(y @ Wyg)
      f32x4 dm0 = {0.f,0.f,0.f,0.f}, dm1 = {0.f,0.f,0.f,0.f}, dgv = {0.f,0.f,0.f,0.f};
#pragma unroll
      for (int ss = 0; ss < 4; ++ss) {
        const int c0 = 32 * ss + g * 8;
        s16x8 av = *(const s16x8*)&bufB[lm * AST + c0];
        s16x8 b0 = *(const s16x8*)&Wob[(32 * wv + lm) * 128 + c0];
        s16x8 b1 = *(const s16x8*)&Wob[(32 * wv + 16 + lm) * 128 + c0];
        s16x8 bg = *(const s16x8*)&Wyb[(16 * wv + lm) * 128 + c0];
        dm0 = MFMA(av, b0, dm0); dm1 = MFMA(av, b1, dm1);
        dgv = MFMA(av, bg, dgv);
      }
#pragma unroll
      for (int r = 0; r < 4; ++r) {
        mres[(4 * g + r) * MST + o0] += dm0[r];
        mres[(4 * g + r) * MST + o1] += dm1[r];
        gres[(4 * g + r) * GST + og] += fast_silu(dgv[r]);
      }
    }
    __syncthreads();   // residuals stable for scatter

    for (int j = tid; j < tlen * 192; j += 256) {
      const int tt = j / 192, ch = j - tt * 192;
      const float w = sc_w[tt];
      if (w != 0.f) {
        const int tgt = sc_i[tt];
        if (ch < CC) atomicAdd(&accm[tgt * CC + ch], mres[tt * MST + ch] * w);
        else         atomicAdd(&accg[tgt * GG + (ch - CC)], gres[tt * GST + (ch - CC)] * w);
      }
    }
    __syncthreads();   // scatter done before next tile overwrites tiles
  }
}

extern "C" void kernel_launch(void* const* d_in, const int* in_sizes, int n_in,
                              void* d_out, int out_size, void* d_ws, size_t ws_size,
                              hipStream_t stream) {
  (void)in_sizes; (void)n_in; (void)out_size; (void)ws_size;
  float* ws = (float*)d_ws;
  KArgs a;
  a.fm[0]  = (const float*)d_in[0]; a.fm[1]  = (const float*)d_in[1];
  a.fg[0]  = (const float*)d_in[2]; a.fg[1]  = (const float*)d_in[3];
  a.flow[0] = (const float*)d_in[4]; a.flow[1] = (const float*)d_in[5];
  a.sx[0] = (const float*)d_in[6]; a.sy[0] = (const float*)d_in[7];
  a.sx[1] = (const float*)d_in[8]; a.sy[1] = (const float*)d_in[9];
  a.Wi  = (const float*)d_in[10]; a.Wz   = (const float*)d_in[11];
  a.Wdt = (const float*)d_in[12]; a.bdt  = (const float*)d_in[13];
  a.alog = (const float*)d_in[14]; a.Wo  = (const float*)d_in[15];
  a.Wyg = (const float*)d_in[16];
  a.fmT[0] = ws + OFF_FMT0; a.fmT[1] = ws + OFF_FMT1;
  a.fgT[0] = ws + OFF_FGT0; a.fgT[1] = ws + OFF_FGT1;
  a.accm[0] = ws + OFF_ACCM0; a.accm[1] = ws + OFF_ACCM1;
  a.accg[0] = ws + OFF_ACCG0; a.accg[1] = ws + OFF_ACCG1;
  a.accw[0] = ws + OFF_ACCW0; a.accw[1] = ws + OFF_ACCW1;
  a.cnt  = (int*)(ws + OFF_CNT);
  a.cnt2 = (int*)(ws + OFF_CNT2);
  a.njobs = (int*)(ws + OFF_NJOBS);
  a.job  = (int*)(ws + OFF_JOB);
  a.wb   = (unsigned short*)(ws + OFF_WB);
  a.out = (float*)d_out;

  k_zero<<<1183, 256, 0, stream>>>(ws + OFF_ACCM0, ACC_FLOATS + 12);
  k_prep<<<1176, 256, 0, stream>>>(a);
  k_prepw<<<1536, 256, 0, stream>>>(a);
  k_count<<<7, 256, 0, stream>>>(a);
  k_assign<<<7, 256, 0, stream>>>(a);
  k_main<<<1568, 256, 0, stream>>>(a);
  k_fin<<<1176, 256, 0, stream>>>(a);
}